// Round 4
// baseline (716.339 us; speedup 1.0000x reference)
//
#include <hip/hip_runtime.h>
#include <math.h>

#define DIM 300
#define NN 127
#define KP 320
#define MATSZ (KP*KP)

typedef short bf16x8 __attribute__((ext_vector_type(8)));
typedef float f32x16 __attribute__((ext_vector_type(16)));

__device__ __forceinline__ unsigned short f2bf(float f){
    unsigned u = __float_as_uint(f);
    u += 0x7fffu + ((u >> 16) & 1u);
    return (unsigned short)(u >> 16);
}
__device__ __forceinline__ float sigf(float v){ return 1.0f/(1.0f+__expf(-v)); }
__device__ __forceinline__ float tanh_(float v){
    float t = __expf(-2.0f*fabsf(v));
    float r = (1.0f - t)/(1.0f + t);
    return v < 0.0f ? -r : r;
}

#define MFMA __builtin_amdgcn_mfma_f32_32x32x16_bf16

// ---- one-time: transpose + bf16-convert weights into WT[8][320 n][320 k] ----
// mats 0..2: Wioux i,o,u ; 3..5: Wiouh i,o,u ; 6: Wfx ; 7: Wfh. Pads are 0.
__global__ void prep_weights(const float* __restrict__ Wioux,
                             const float* __restrict__ Wiouh,
                             const float* __restrict__ Wfx,
                             const float* __restrict__ Wfh,
                             unsigned short* __restrict__ WT)
{
    int k = threadIdx.x;     // 0..319
    int n = blockIdx.x;      // 0..319
    int m = blockIdx.y;      // 0..7
    float v = 0.f;
    if (k < DIM && n < DIM){
        if (m < 3)       v = Wioux[k*(3*DIM) + m*DIM + n];
        else if (m < 6)  v = Wiouh[k*(3*DIM) + (m-3)*DIM + n];
        else if (m == 6) v = Wfx[k*DIM + n];
        else             v = Wfh[k*DIM + n];
    }
    WT[m*MATSZ + n*KP + k] = f2bf(v);
}

// ---- one-time: x fp32 -> bf16, rows padded to 320 (pad = 0) ----
__global__ void prep_x(const float* __restrict__ x, unsigned short* __restrict__ xbf)
{
    int row = blockIdx.x;        // 0..65023 (b*127+node)
    int t = threadIdx.x;         // 0..319
    float v = (t < DIM) ? x[row*DIM + t] : 0.f;
    xbf[row*KP + t] = f2bf(v);
}

// ==================== leaf level: nodes 63..126 (no LDS, no barriers) ====================
__global__ __launch_bounds__(256,2)
void leaf_mfma(const unsigned short* __restrict__ xbf,
               const float* __restrict__ bioux, const float* __restrict__ biouh,
               const unsigned short* __restrict__ WT,
               float* __restrict__ H, float* __restrict__ C,
               unsigned short* __restrict__ hbf)
{
    const int t = threadIdx.x, lane = t & 63, wave = t >> 6;
    const int wm = wave >> 1, wn = wave & 1;
    const int lrow = lane & 31, half = lane >> 5;
    const int rowBase = blockIdx.x * 128, d0 = blockIdx.y * 64;

    const unsigned short* xr[2];
    #pragma unroll
    for (int rt = 0; rt < 2; rt++){
        int grow = rowBase + wm*64 + rt*32 + lrow;
        int b = grow >> 6, j = 63 + (grow & 63);
        xr[rt] = xbf + (b*NN + j)*KP + half*8;
    }
    const unsigned short* wb = WT + (d0 + wn*32 + lrow)*KP + half*8;

    f32x16 accI[2], accO[2], accU[2];
    #pragma unroll
    for (int rt = 0; rt < 2; rt++)
        #pragma unroll
        for (int q = 0; q < 16; q++){ accI[rt][q]=0.f; accO[rt][q]=0.f; accU[rt][q]=0.f; }

    #pragma unroll
    for (int ks = 0; ks < 10; ks++){
        #pragma unroll
        for (int kk = 0; kk < 2; kk++){
            const int off = ks*32 + kk*16;
            bf16x8 b0 = *(const bf16x8*)(wb + 0*MATSZ + off);
            bf16x8 b1 = *(const bf16x8*)(wb + 1*MATSZ + off);
            bf16x8 b2 = *(const bf16x8*)(wb + 2*MATSZ + off);
            #pragma unroll
            for (int rt = 0; rt < 2; rt++){
                bf16x8 ax = *(const bf16x8*)(xr[rt] + off);
                accI[rt] = MFMA(ax, b0, accI[rt], 0, 0, 0);
                accO[rt] = MFMA(ax, b1, accO[rt], 0, 0, 0);
                accU[rt] = MFMA(ax, b2, accU[rt], 0, 0, 0);
            }
        }
    }
    int d = d0 + wn*32 + lrow;
    if (d < DIM){
        float bi  = bioux[d]       + biouh[d];
        float bo_ = bioux[DIM+d]   + biouh[DIM+d];
        float bu  = bioux[2*DIM+d] + biouh[2*DIM+d];
        #pragma unroll
        for (int rt = 0; rt < 2; rt++)
            #pragma unroll
            for (int q = 0; q < 16; q++){
                int grow = rowBase + wm*64 + rt*32 + (q&3) + 8*(q>>2) + 4*half;
                int b = grow >> 6, j = 63 + (grow & 63);
                int nb = b*NN + j;
                float iv = sigf (accI[rt][q] + bi);
                float ov = sigf (accO[rt][q] + bo_);
                float uv = tanh_(accU[rt][q] + bu);
                float cv = iv*uv;
                float hv = ov*tanh_(cv);
                C[nb*DIM + d] = cv;
                H[nb*DIM + d] = hv;
                hbf[nb*KP + d] = f2bf(hv);
            }
    }
}

// ==================== internal levels (no LDS, no barriers) ====================
__global__ __launch_bounds__(256,2)
void level_mfma(const unsigned short* __restrict__ xbf,
                const unsigned short* __restrict__ hbf,
                const float* __restrict__ bioux, const float* __restrict__ biouh,
                const float* __restrict__ bfx,   const float* __restrict__ bfh,
                const unsigned short* __restrict__ WT,
                float* __restrict__ H, float* __restrict__ C,
                unsigned short* __restrict__ hbf_out,
                int lo, int lshift)
{
    const int t = threadIdx.x, lane = t & 63, wave = t >> 6;
    const int wm = wave >> 1, wn = wave & 1;
    const int lrow = lane & 31, half = lane >> 5;
    const int rowBase = blockIdx.x * 128, d0 = blockIdx.y * 64;
    const int nmask = (1 << lshift) - 1;

    const unsigned short *xr[2], *h0r[2], *h1r[2];
    #pragma unroll
    for (int rt = 0; rt < 2; rt++){
        int grow = rowBase + wm*64 + rt*32 + lrow;
        int b = grow >> lshift, j = lo + (grow & nmask);
        xr[rt]  = xbf + (b*NN + j)*KP + half*8;
        h0r[rt] = hbf + (b*NN + 2*j+1)*KP + half*8;
        h1r[rt] = hbf + (b*NN + 2*j+2)*KP + half*8;
    }
    const unsigned short* wb = WT + (d0 + wn*32 + lrow)*KP + half*8;

    f32x16 accI[2], accO[2], accU[2], accF0[2], accF1[2];
    #pragma unroll
    for (int rt = 0; rt < 2; rt++)
        #pragma unroll
        for (int q = 0; q < 16; q++){
            accI[rt][q]=0.f; accO[rt][q]=0.f; accU[rt][q]=0.f;
            accF0[rt][q]=0.f; accF1[rt][q]=0.f;
        }

    #pragma unroll
    for (int ks = 0; ks < 10; ks++){
        #pragma unroll
        for (int kk = 0; kk < 2; kk++){
            const int off = ks*32 + kk*16;
            bf16x8 b0 = *(const bf16x8*)(wb + 0*MATSZ + off);
            bf16x8 b1 = *(const bf16x8*)(wb + 1*MATSZ + off);
            bf16x8 b2 = *(const bf16x8*)(wb + 2*MATSZ + off);
            bf16x8 b3 = *(const bf16x8*)(wb + 3*MATSZ + off);
            bf16x8 b4 = *(const bf16x8*)(wb + 4*MATSZ + off);
            bf16x8 b5 = *(const bf16x8*)(wb + 5*MATSZ + off);
            bf16x8 b6 = *(const bf16x8*)(wb + 6*MATSZ + off);
            bf16x8 b7 = *(const bf16x8*)(wb + 7*MATSZ + off);
            #pragma unroll
            for (int rt = 0; rt < 2; rt++){
                bf16x8 ax = *(const bf16x8*)(xr[rt]  + off);
                bf16x8 a0 = *(const bf16x8*)(h0r[rt] + off);
                bf16x8 a1 = *(const bf16x8*)(h1r[rt] + off);
                accI[rt]  = MFMA(ax, b0, accI[rt], 0, 0, 0);
                accI[rt]  = MFMA(a0, b3, accI[rt], 0, 0, 0);
                accI[rt]  = MFMA(a1, b3, accI[rt], 0, 0, 0);
                accO[rt]  = MFMA(ax, b1, accO[rt], 0, 0, 0);
                accO[rt]  = MFMA(a0, b4, accO[rt], 0, 0, 0);
                accO[rt]  = MFMA(a1, b4, accO[rt], 0, 0, 0);
                accU[rt]  = MFMA(ax, b2, accU[rt], 0, 0, 0);
                accU[rt]  = MFMA(a0, b5, accU[rt], 0, 0, 0);
                accU[rt]  = MFMA(a1, b5, accU[rt], 0, 0, 0);
                accF0[rt] = MFMA(ax, b6, accF0[rt], 0, 0, 0);
                accF0[rt] = MFMA(a0, b7, accF0[rt], 0, 0, 0);
                accF1[rt] = MFMA(ax, b6, accF1[rt], 0, 0, 0);
                accF1[rt] = MFMA(a1, b7, accF1[rt], 0, 0, 0);
            }
        }
    }
    int d = d0 + wn*32 + lrow;
    if (d < DIM){
        float bi  = bioux[d]       + biouh[d];
        float bo_ = bioux[DIM+d]   + biouh[DIM+d];
        float bu  = bioux[2*DIM+d] + biouh[2*DIM+d];
        float bf_ = bfx[d] + bfh[d];
        #pragma unroll
        for (int rt = 0; rt < 2; rt++)
            #pragma unroll
            for (int q = 0; q < 16; q++){
                int grow = rowBase + wm*64 + rt*32 + (q&3) + 8*(q>>2) + 4*half;
                int b = grow >> lshift, j = lo + (grow & nmask);
                int nb = b*NN + j;
                float c0 = C[(b*NN + 2*j+1)*DIM + d];
                float c1 = C[(b*NN + 2*j+2)*DIM + d];
                float iv = sigf (accI[rt][q] + bi);
                float ov = sigf (accO[rt][q] + bo_);
                float uv = tanh_(accU[rt][q] + bu);
                float f0 = sigf (accF0[rt][q] + bf_);
                float f1 = sigf (accF1[rt][q] + bf_);
                float cv = iv*uv + f0*c0 + f1*c1;
                float hv = ov*tanh_(cv);
                C[nb*DIM + d] = cv;
                H[nb*DIM + d] = hv;
                hbf_out[nb*KP + d] = f2bf(hv);
            }
    }
}

extern "C" void kernel_launch(void* const* d_in, const int* in_sizes, int n_in,
                              void* d_out, int out_size, void* d_ws, size_t ws_size,
                              hipStream_t stream) {
    const float* x     = (const float*)d_in[0];
    const float* Wioux = (const float*)d_in[1];
    const float* bioux = (const float*)d_in[2];
    const float* Wiouh = (const float*)d_in[3];
    const float* biouh = (const float*)d_in[4];
    const float* Wfx   = (const float*)d_in[5];
    const float* bfx   = (const float*)d_in[6];
    const float* Wfh   = (const float*)d_in[7];
    const float* bfh   = (const float*)d_in[8];
    float* H = (float*)d_out;
    // ws layout: C fp32 78,028,800 | WT 1,638,400 | xbf 41,615,360 | hbf 41,615,360  (~163 MB)
    float* C = (float*)d_ws;
    unsigned short* WT  = (unsigned short*)((char*)d_ws + 78028800);
    unsigned short* xbf = (unsigned short*)((char*)d_ws + 79667200);
    unsigned short* hbf = (unsigned short*)((char*)d_ws + 121282560);

    prep_weights<<<dim3(KP, 8), KP, 0, stream>>>(Wioux, Wiouh, Wfx, Wfh, WT);
    prep_x<<<dim3(512*NN), KP, 0, stream>>>(x, xbf);
    // leaves: 32768 rows -> 256 x 5 blocks
    leaf_mfma<<<dim3(256, 5), 256, 0, stream>>>(xbf, bioux, biouh, WT, H, C, hbf);
    // internal levels deepest-first: rows = 512<<l -> (4<<l) x 5 blocks
    for (int l = 5; l >= 0; l--){
        level_mfma<<<dim3(4 << l, 5), 256, 0, stream>>>(
            xbf, hbf, bioux, biouh, bfx, bfh, WT, H, C, hbf, (1 << l) - 1, l);
    }
}

// Round 5
// 586.373 us; speedup vs baseline: 1.2216x; 1.2216x over previous
//
#include <hip/hip_runtime.h>
#include <math.h>

#define DIM 300
#define NN 127
#define KP 320
#define MATSZ (KP*KP)          // 102400 shorts per weight matrix
#define RBSZ 10240             // shorts per 32-row fragment block (32 rows x 320 k)
#define SZH 10321920           // shorts per hF stream (32256 parent rows x 320)

typedef short bf16x8 __attribute__((ext_vector_type(8)));
typedef float f32x16 __attribute__((ext_vector_type(16)));

__device__ __forceinline__ unsigned short f2bf(float f){
    unsigned u = __float_as_uint(f);
    u += 0x7fffu + ((u >> 16) & 1u);
    return (unsigned short)(u >> 16);
}
__device__ __forceinline__ float sigf(float v){ return 1.0f/(1.0f+__expf(-v)); }
__device__ __forceinline__ float tanh_(float v){
    float t = __expf(-2.0f*fabsf(v));
    float r = (1.0f - t)/(1.0f + t);
    return v < 0.0f ? -r : r;
}

#define MFMA __builtin_amdgcn_mfma_f32_32x32x16_bf16

// Fragment layout: a 32-row x 320-k panel occupies RBSZ shorts:
//   addr = rb*RBSZ + ks*1024 + kk*512 + half*256 + row*8 + e
// where k = ks*32 + kk*16 + half*8 + e. Lane l of a wave reads at lane*8 with
// half=(l>>5), row=(l&31) -> one contiguous 1KB dwordx4 load per fragment.

// ---- weights -> fragment layout WTF[8 mats][10 nblk][RBSZ] ----
__global__ void prep_weights(const float* __restrict__ Wioux,
                             const float* __restrict__ Wiouh,
                             const float* __restrict__ Wfx,
                             const float* __restrict__ Wfh,
                             unsigned short* __restrict__ WTF)
{
    int k = threadIdx.x;     // 0..319
    int n = blockIdx.x;      // 0..319
    int m = blockIdx.y;      // 0..7
    float v = 0.f;
    if (k < DIM && n < DIM){
        if (m < 3)       v = Wioux[k*(3*DIM) + m*DIM + n];
        else if (m < 6)  v = Wiouh[k*(3*DIM) + (m-3)*DIM + n];
        else if (m == 6) v = Wfx[k*DIM + n];
        else             v = Wfh[k*DIM + n];
    }
    int dst = m*MATSZ + (n>>5)*RBSZ + (k>>5)*1024 + ((k>>4)&1)*512
            + (((k>>3)&1)*32 + (n&31))*8 + (k&7);
    WTF[dst] = f2bf(v);
}

// ---- x -> per-level fragment layout. Level lev slot starts at row 512*lo. ----
__global__ void prep_x(const float* __restrict__ x, unsigned short* __restrict__ xF)
{
    int id = blockIdx.x;                 // 0..65023 = b*127+j
    int b = id / NN, j = id - b*NN;
    int lev = 31 - __clz(j + 1);
    int lo = (1 << lev) - 1;
    int r = b*(1 << lev) + (j - lo);
    int rb32 = 16*lo + (r >> 5), ri = r & 31;
    int t = threadIdx.x;                 // 0..319
    float v = (t < DIM) ? x[id*DIM + t] : 0.f;
    xF[rb32*RBSZ + (t>>5)*1024 + ((t>>4)&1)*512 + (((t>>3)&1)*32 + ri)*8 + (t&7)] = f2bf(v);
}

// ==================== leaf level: nodes 63..126 ====================
__global__ __launch_bounds__(256,2)
void leaf_mfma(const unsigned short* __restrict__ xF,
               const unsigned short* __restrict__ WTF,
               const float* __restrict__ bioux, const float* __restrict__ biouh,
               float* __restrict__ H, float* __restrict__ C,
               unsigned short* __restrict__ hF)
{
    const int t = threadIdx.x, lane = t & 63, wave = t >> 6;
    const int wm = wave >> 1, wn = wave & 1;
    const int grow0 = blockIdx.x*64 + wm*32;
    const int d0 = blockIdx.y*64 + wn*32;

    const unsigned short* ap = xF + (16*63 + (grow0 >> 5))*RBSZ + lane*8;
    const unsigned short* bp = WTF + (d0 >> 5)*RBSZ + lane*8;

    f32x16 aI, aO, aU;
    #pragma unroll
    for (int q = 0; q < 16; q++){ aI[q]=0.f; aO[q]=0.f; aU[q]=0.f; }

    #pragma unroll
    for (int ks = 0; ks < 10; ks++){
        #pragma unroll
        for (int kk = 0; kk < 2; kk++){
            const int off = ks*1024 + kk*512;
            bf16x8 ax = *(const bf16x8*)(ap + off);
            bf16x8 b0 = *(const bf16x8*)(bp + 0*MATSZ + off);
            bf16x8 b1 = *(const bf16x8*)(bp + 1*MATSZ + off);
            bf16x8 b2 = *(const bf16x8*)(bp + 2*MATSZ + off);
            aI = MFMA(ax, b0, aI, 0, 0, 0);
            aO = MFMA(ax, b1, aO, 0, 0, 0);
            aU = MFMA(ax, b2, aU, 0, 0, 0);
        }
    }
    int d = d0 + (lane & 31);
    if (d < DIM){
        float bi  = bioux[d]       + biouh[d];
        float bo_ = bioux[DIM+d]   + biouh[DIM+d];
        float bu  = bioux[2*DIM+d] + biouh[2*DIM+d];
        #pragma unroll
        for (int q = 0; q < 16; q++){
            int grow = grow0 + (q&3) + 8*(q>>2) + 4*(lane>>5);
            int b = grow >> 6, j = 63 + (grow & 63);
            int nb = b*NN + j;
            float iv = sigf (aI[q] + bi);
            float ov = sigf (aO[q] + bo_);
            float uv = tanh_(aU[q] + bu);
            float cv = iv*uv;
            float hv = ov*tanh_(cv);
            C[nb*DIM + d] = cv;
            H[nb*DIM + d] = hv;
            // write h into parent (level 5) fragment slot
            int jp = (j - 1) >> 1, s = 1 - (j & 1);
            int rp = b*32 + (jp - 31);
            int dst = s*SZH + (16*31 + (rp>>5))*RBSZ + (d>>5)*1024 + ((d>>4)&1)*512
                    + (((d>>3)&1)*32 + (rp&31))*8 + (d&7);
            hF[dst] = f2bf(hv);
        }
    }
}

// ==================== internal levels ====================
__global__ __launch_bounds__(256,2)
void level_mfma(const unsigned short* __restrict__ xF,
                const unsigned short* __restrict__ hF,
                const unsigned short* __restrict__ WTF,
                const float* __restrict__ bioux, const float* __restrict__ biouh,
                const float* __restrict__ bfx,   const float* __restrict__ bfh,
                float* __restrict__ H, float* __restrict__ C,
                unsigned short* __restrict__ hFw,
                int lshift)
{
    const int t = threadIdx.x, lane = t & 63, wave = t >> 6;
    const int wm = wave >> 1, wn = wave & 1;
    const int grow0 = blockIdx.x*64 + wm*32;
    const int d0 = blockIdx.y*64 + wn*32;
    const int lo = (1 << lshift) - 1;

    const int base32 = 16*lo + (grow0 >> 5);
    const unsigned short* ap  = xF + base32*RBSZ + lane*8;
    const unsigned short* h0p = hF + base32*RBSZ + lane*8;
    const unsigned short* h1p = h0p + SZH;
    const unsigned short* bp  = WTF + (d0 >> 5)*RBSZ + lane*8;

    f32x16 aI, aO, aU, aF0, aF1;
    #pragma unroll
    for (int q = 0; q < 16; q++){
        aI[q]=0.f; aO[q]=0.f; aU[q]=0.f; aF0[q]=0.f; aF1[q]=0.f;
    }

    #pragma unroll
    for (int ks = 0; ks < 10; ks++){
        #pragma unroll
        for (int kk = 0; kk < 2; kk++){
            const int off = ks*1024 + kk*512;
            bf16x8 ax = *(const bf16x8*)(ap  + off);
            bf16x8 a0 = *(const bf16x8*)(h0p + off);
            bf16x8 a1 = *(const bf16x8*)(h1p + off);
            bf16x8 b0 = *(const bf16x8*)(bp + 0*MATSZ + off);
            bf16x8 b1 = *(const bf16x8*)(bp + 1*MATSZ + off);
            bf16x8 b2 = *(const bf16x8*)(bp + 2*MATSZ + off);
            bf16x8 b3 = *(const bf16x8*)(bp + 3*MATSZ + off);
            bf16x8 b4 = *(const bf16x8*)(bp + 4*MATSZ + off);
            bf16x8 b5 = *(const bf16x8*)(bp + 5*MATSZ + off);
            bf16x8 b6 = *(const bf16x8*)(bp + 6*MATSZ + off);
            bf16x8 b7 = *(const bf16x8*)(bp + 7*MATSZ + off);
            aI  = MFMA(ax, b0, aI , 0, 0, 0);
            aI  = MFMA(a0, b3, aI , 0, 0, 0);
            aI  = MFMA(a1, b3, aI , 0, 0, 0);
            aO  = MFMA(ax, b1, aO , 0, 0, 0);
            aO  = MFMA(a0, b4, aO , 0, 0, 0);
            aO  = MFMA(a1, b4, aO , 0, 0, 0);
            aU  = MFMA(ax, b2, aU , 0, 0, 0);
            aU  = MFMA(a0, b5, aU , 0, 0, 0);
            aU  = MFMA(a1, b5, aU , 0, 0, 0);
            aF0 = MFMA(ax, b6, aF0, 0, 0, 0);
            aF0 = MFMA(a0, b7, aF0, 0, 0, 0);
            aF1 = MFMA(ax, b6, aF1, 0, 0, 0);
            aF1 = MFMA(a1, b7, aF1, 0, 0, 0);
        }
    }
    int d = d0 + (lane & 31);
    if (d < DIM){
        float bi  = bioux[d]       + biouh[d];
        float bo_ = bioux[DIM+d]   + biouh[DIM+d];
        float bu  = bioux[2*DIM+d] + biouh[2*DIM+d];
        float bf_ = bfx[d] + bfh[d];
        #pragma unroll
        for (int q = 0; q < 16; q++){
            int grow = grow0 + (q&3) + 8*(q>>2) + 4*(lane>>5);
            int b = grow >> lshift, j = lo + (grow & lo);
            int nb = b*NN + j;
            float c0 = C[(b*NN + 2*j+1)*DIM + d];
            float c1 = C[(b*NN + 2*j+2)*DIM + d];
            float iv = sigf (aI[q] + bi);
            float ov = sigf (aO[q] + bo_);
            float uv = tanh_(aU[q] + bu);
            float f0 = sigf (aF0[q] + bf_);
            float f1 = sigf (aF1[q] + bf_);
            float cv = iv*uv + f0*c0 + f1*c1;
            float hv = ov*tanh_(cv);
            C[nb*DIM + d] = cv;
            H[nb*DIM + d] = hv;
            if (lshift > 0){
                int jp = (j - 1) >> 1, s = 1 - (j & 1);
                int lop = (1 << (lshift-1)) - 1;
                int rp = b*(1 << (lshift-1)) + (jp - lop);
                int dst = s*SZH + (16*lop + (rp>>5))*RBSZ + (d>>5)*1024 + ((d>>4)&1)*512
                        + (((d>>3)&1)*32 + (rp&31))*8 + (d&7);
                hFw[dst] = f2bf(hv);
            }
        }
    }
}

extern "C" void kernel_launch(void* const* d_in, const int* in_sizes, int n_in,
                              void* d_out, int out_size, void* d_ws, size_t ws_size,
                              hipStream_t stream) {
    const float* x     = (const float*)d_in[0];
    const float* Wioux = (const float*)d_in[1];
    const float* bioux = (const float*)d_in[2];
    const float* Wiouh = (const float*)d_in[3];
    const float* biouh = (const float*)d_in[4];
    const float* Wfx   = (const float*)d_in[5];
    const float* bfx   = (const float*)d_in[6];
    const float* Wfh   = (const float*)d_in[7];
    const float* bfh   = (const float*)d_in[8];
    float* H = (float*)d_out;
    // ws: C fp32 78,028,800 | WTF 1,638,400 | xF 41,615,360 | hF 2x20,643,840 = 162,570,240 B
    float* C = (float*)d_ws;
    unsigned short* WTF = (unsigned short*)((char*)d_ws + 78028800);
    unsigned short* xF  = (unsigned short*)((char*)d_ws + 79667200);
    unsigned short* hF  = (unsigned short*)((char*)d_ws + 121282560);

    hipMemsetAsync(hF, 0, (size_t)SZH*2*2, stream);   // zero k-pads of h fragments
    prep_weights<<<dim3(KP, 8), KP, 0, stream>>>(Wioux, Wiouh, Wfx, Wfh, WTF);
    prep_x<<<dim3(512*NN), KP, 0, stream>>>(x, xF);
    // leaves: 32768 rows
    leaf_mfma<<<dim3(512, 5), 256, 0, stream>>>(xF, WTF, bioux, biouh, H, C, hF);
    // internal levels deepest-first: rows = 512<<l
    for (int l = 5; l >= 0; l--){
        level_mfma<<<dim3(8 << l, 5), 256, 0, stream>>>(
            xF, hF, WTF, bioux, biouh, bfx, bfh, H, C, hF, l);
    }
}